// Round 1
// baseline (376.948 us; speedup 1.0000x reference)
//
#include <hip/hip_runtime.h>

#define NBINS 256

// ---------------------------------------------------------------------------
// Kernel 1: per-channel histogram.
// Grid = nch * blocks_per_ch blocks of 256 threads. Each block owns a
// contiguous chunk of ONE channel (so the channel id is uniform per block).
// 4 per-wave LDS histogram replicas to reduce LDS-atomic contention.
// ---------------------------------------------------------------------------
__global__ __launch_bounds__(256) void eq_hist(const float4* __restrict__ img,
                                               unsigned int* __restrict__ ghist,
                                               int n4_per_ch, int blocks_per_ch) {
    __shared__ unsigned int lh[4][NBINS];
    const int t = threadIdx.x;
    const int w = t >> 6;  // wave id (wave64)
    for (int i = t; i < 4 * NBINS; i += 256) ((unsigned int*)lh)[i] = 0u;
    __syncthreads();

    const int ch  = blockIdx.x / blocks_per_ch;
    const int blk = blockIdx.x - ch * blocks_per_ch;
    const int per = n4_per_ch / blocks_per_ch;               // float4s per block
    const size_t base = (size_t)ch * n4_per_ch + (size_t)blk * per;

    for (int i = t; i < per; i += 256) {
        float4 v = img[base + i];
        // Identical fp32 op sequence to jnp: clip(x,0,1)*255 then trunc-to-int.
        int q0 = (int)(fminf(fmaxf(v.x, 0.f), 1.f) * 255.0f);
        int q1 = (int)(fminf(fmaxf(v.y, 0.f), 1.f) * 255.0f);
        int q2 = (int)(fminf(fmaxf(v.z, 0.f), 1.f) * 255.0f);
        int q3 = (int)(fminf(fmaxf(v.w, 0.f), 1.f) * 255.0f);
        atomicAdd(&lh[w][q0], 1u);
        atomicAdd(&lh[w][q1], 1u);
        atomicAdd(&lh[w][q2], 1u);
        atomicAdd(&lh[w][q3], 1u);
    }
    __syncthreads();

    // 256 threads, 256 bins: one bin each. Merge the 4 replicas, one global
    // atomic per nonzero bin.
    unsigned int s = lh[0][t] + lh[1][t] + lh[2][t] + lh[3][t];
    if (s) atomicAdd(&ghist[ch * NBINS + t], s);
}

// ---------------------------------------------------------------------------
// Kernel 2: per-channel CDF -> LUT. One block (256 threads) per channel.
// Counts are integers <= 2^20 so integer cumsum == fp32 cumsum exactly.
// ---------------------------------------------------------------------------
__global__ __launch_bounds__(256) void eq_lut(const unsigned int* __restrict__ ghist,
                                              float* __restrict__ lut, int n_pixels) {
    __shared__ unsigned int sc[NBINS];
    __shared__ unsigned int rm[NBINS];
    const int ch = blockIdx.x;
    const int t  = threadIdx.x;

    sc[t] = ghist[ch * NBINS + t];
    __syncthreads();

    // Hillis-Steele inclusive scan.
    for (int off = 1; off < NBINS; off <<= 1) {
        unsigned int add = (t >= off) ? sc[t - off] : 0u;
        __syncthreads();
        sc[t] += add;
        __syncthreads();
    }
    const unsigned int cdf = sc[t];

    // min over positive cdf values (cdf nondecreasing, total = n_pixels > 0).
    rm[t] = cdf ? cdf : 0xFFFFFFFFu;
    __syncthreads();
    for (int off = NBINS / 2; off > 0; off >>= 1) {
        if (t < off) rm[t] = min(rm[t], rm[t + off]);
        __syncthreads();
    }
    const unsigned int cmin = rm[0];

    // Reference: (cdf - cdf_min) / (n_pixels - cdf_min + 1e-8), all fp32.
    const float denom = (float)(n_pixels - (int)cmin) + 1e-8f;
    lut[ch * NBINS + t] = ((float)cdf - (float)cmin) / denom;
}

// ---------------------------------------------------------------------------
// Kernel 3: remap pixels through the per-channel LUT (staged in LDS).
// ---------------------------------------------------------------------------
__global__ __launch_bounds__(256) void eq_remap(const float4* __restrict__ img,
                                                const float* __restrict__ lut,
                                                float4* __restrict__ out,
                                                int n4_per_ch, int blocks_per_ch) {
    __shared__ float sl[NBINS];
    const int t = threadIdx.x;
    const int ch  = blockIdx.x / blocks_per_ch;
    const int blk = blockIdx.x - ch * blocks_per_ch;

    sl[t] = lut[ch * NBINS + t];
    __syncthreads();

    const int per = n4_per_ch / blocks_per_ch;
    const size_t base = (size_t)ch * n4_per_ch + (size_t)blk * per;

    for (int i = t; i < per; i += 256) {
        float4 v = img[base + i];
        float4 o;
        o.x = sl[(int)(fminf(fmaxf(v.x, 0.f), 1.f) * 255.0f)];
        o.y = sl[(int)(fminf(fmaxf(v.y, 0.f), 1.f) * 255.0f)];
        o.z = sl[(int)(fminf(fmaxf(v.z, 0.f), 1.f) * 255.0f)];
        o.w = sl[(int)(fminf(fmaxf(v.w, 0.f), 1.f) * 255.0f)];
        out[base + i] = o;
    }
}

extern "C" void kernel_launch(void* const* d_in, const int* in_sizes, int n_in,
                              void* d_out, int out_size, void* d_ws, size_t ws_size,
                              hipStream_t stream) {
    const float* img = (const float*)d_in[0];
    float* out = (float*)d_out;

    const int n_pixels  = 1024 * 1024;              // H*W per reference
    const int nch       = in_sizes[0] / n_pixels;   // B*C = 48
    const int n4_per_ch = n_pixels / 4;             // float4 per channel

    unsigned int* ghist = (unsigned int*)d_ws;
    float* lut = (float*)((char*)d_ws + (size_t)nch * NBINS * sizeof(unsigned int));

    // Zero the global histograms (d_ws is poisoned 0xAA before every launch).
    hipMemsetAsync(ghist, 0, (size_t)nch * NBINS * sizeof(unsigned int), stream);

    const int bpc = 32;  // blocks per channel -> 1536 blocks total
    eq_hist <<<nch * bpc, 256, 0, stream>>>((const float4*)img, ghist, n4_per_ch, bpc);
    eq_lut  <<<nch,       256, 0, stream>>>(ghist, lut, n_pixels);
    eq_remap<<<nch * bpc, 256, 0, stream>>>((const float4*)img, lut, (float4*)out, n4_per_ch, bpc);
}

// Round 3
// 337.443 us; speedup vs baseline: 1.1171x; 1.1171x over previous
//
#include <hip/hip_runtime.h>

#define NBINS 256

// Native clang vector type: __builtin_nontemporal_* requires this (the HIP
// float4 class type is rejected by the builtin).
typedef float f4_t __attribute__((ext_vector_type(4)));

// ---------------------------------------------------------------------------
// Kernel 1: quantize + per-channel histogram.
// Each block owns a contiguous chunk of ONE channel. Writes the quantized
// byte indices to qout (reused by remap, avoiding a second 201 MB img read).
// 4 per-wave LDS histogram replicas cut same-address atomic collisions.
// img is read-once -> nontemporal loads keep L3 free for q.
// ---------------------------------------------------------------------------
__global__ __launch_bounds__(256) void eq_hist(const f4_t* __restrict__ img,
                                               uchar4* __restrict__ qout,
                                               unsigned int* __restrict__ ghist,
                                               int n4_per_ch, int blocks_per_ch) {
    __shared__ unsigned int lh[4][NBINS];
    const int t = threadIdx.x;
    const int w = t >> 6;  // wave id (wave64)
    for (int i = t; i < 4 * NBINS; i += 256) ((unsigned int*)lh)[i] = 0u;
    __syncthreads();

    const int ch  = blockIdx.x / blocks_per_ch;
    const int blk = blockIdx.x - ch * blocks_per_ch;
    const int per = n4_per_ch / blocks_per_ch;
    const size_t base = (size_t)ch * n4_per_ch + (size_t)blk * per;

    for (int i = t; i < per; i += 256) {
        f4_t v = __builtin_nontemporal_load(&img[base + i]);
        // Identical fp32 op sequence to jnp: clip(x,0,1)*255 then trunc-to-int.
        int q0 = (int)(fminf(fmaxf(v.x, 0.f), 1.f) * 255.0f);
        int q1 = (int)(fminf(fmaxf(v.y, 0.f), 1.f) * 255.0f);
        int q2 = (int)(fminf(fmaxf(v.z, 0.f), 1.f) * 255.0f);
        int q3 = (int)(fminf(fmaxf(v.w, 0.f), 1.f) * 255.0f);
        qout[base + i] = make_uchar4((unsigned char)q0, (unsigned char)q1,
                                     (unsigned char)q2, (unsigned char)q3);
        atomicAdd(&lh[w][q0], 1u);
        atomicAdd(&lh[w][q1], 1u);
        atomicAdd(&lh[w][q2], 1u);
        atomicAdd(&lh[w][q3], 1u);
    }
    __syncthreads();

    // 256 threads, 256 bins: one bin each. Merge replicas, one global atomic
    // per nonzero bin.
    unsigned int s = lh[0][t] + lh[1][t] + lh[2][t] + lh[3][t];
    if (s) atomicAdd(&ghist[ch * NBINS + t], s);
}

// ---------------------------------------------------------------------------
// Kernel 2: CDF -> LUT (computed redundantly per block; 256-bin scan is ~µs)
// then remap the stored byte indices through the LDS LUT.
// Counts are integers <= 2^20 so uint cumsum == jnp fp32 cumsum exactly.
// out is write-once streaming -> nontemporal stores.
// ---------------------------------------------------------------------------
__global__ __launch_bounds__(256) void eq_remap(const uchar4* __restrict__ q,
                                                const unsigned int* __restrict__ ghist,
                                                f4_t* __restrict__ out,
                                                int n4_per_ch, int blocks_per_ch,
                                                int n_pixels) {
    __shared__ unsigned int sc[NBINS];
    __shared__ unsigned int rm[NBINS];
    __shared__ float sl[NBINS];
    const int t = threadIdx.x;
    const int ch  = blockIdx.x / blocks_per_ch;
    const int blk = blockIdx.x - ch * blocks_per_ch;

    sc[t] = ghist[ch * NBINS + t];
    __syncthreads();

    // Hillis-Steele inclusive scan (exact: integer counts).
    for (int off = 1; off < NBINS; off <<= 1) {
        unsigned int add = (t >= off) ? sc[t - off] : 0u;
        __syncthreads();
        sc[t] += add;
        __syncthreads();
    }
    const unsigned int cdf = sc[t];

    // min over positive cdf values.
    rm[t] = cdf ? cdf : 0xFFFFFFFFu;
    __syncthreads();
    for (int off = NBINS / 2; off > 0; off >>= 1) {
        if (t < off) rm[t] = min(rm[t], rm[t + off]);
        __syncthreads();
    }
    const unsigned int cmin = rm[0];

    // Reference: (cdf - cdf_min) / (n_pixels - cdf_min + 1e-8), all fp32.
    // Values <= 2^20 are exactly representable -> bit-identical to jnp.
    const float denom = (float)(n_pixels - (int)cmin) + 1e-8f;
    sl[t] = ((float)cdf - (float)cmin) / denom;
    __syncthreads();

    const int per = n4_per_ch / blocks_per_ch;
    const size_t base = (size_t)ch * n4_per_ch + (size_t)blk * per;

    for (int i = t; i < per; i += 256) {
        uchar4 qq = q[base + i];
        f4_t o = {sl[qq.x], sl[qq.y], sl[qq.z], sl[qq.w]};
        __builtin_nontemporal_store(o, &out[base + i]);
    }
}

extern "C" void kernel_launch(void* const* d_in, const int* in_sizes, int n_in,
                              void* d_out, int out_size, void* d_ws, size_t ws_size,
                              hipStream_t stream) {
    const float* img = (const float*)d_in[0];
    float* out = (float*)d_out;

    const int n_pixels  = 1024 * 1024;              // H*W per reference
    const int nch       = in_sizes[0] / n_pixels;   // B*C = 48
    const int n4_per_ch = n_pixels / 4;

    unsigned int* ghist = (unsigned int*)d_ws;
    uchar4* qbuf = (uchar4*)((char*)d_ws + 65536);  // 64 KB after hist (needs 49 KB)

    // Zero the global histograms (d_ws is poisoned 0xAA before every launch).
    (void)hipMemsetAsync(ghist, 0, (size_t)nch * NBINS * sizeof(unsigned int), stream);

    const int bpc = 64;  // blocks per channel -> 3072 blocks total
    eq_hist <<<nch * bpc, 256, 0, stream>>>((const f4_t*)img, qbuf, ghist,
                                            n4_per_ch, bpc);
    eq_remap<<<nch * bpc, 256, 0, stream>>>(qbuf, ghist, (f4_t*)out,
                                            n4_per_ch, bpc, n_pixels);
}